// Round 16
// baseline (249.456 us; speedup 1.0000x reference)
//
#include <hip/hip_runtime.h>
#include <stdint.h>

#define B_  4
#define T_  2048
#define C_  1024
#define NH_ 16
#define HD_ 64
#define BH_ (B_*NH_)   // 64
#define M_  (B_*T_)    // 8192
#define KT_ 16         // K-tiles (K=1024 / BK=64)

using f32x4  = __attribute__((ext_vector_type(4))) float;
using f32x16 = __attribute__((ext_vector_type(16))) float;
using bf16x8 = __attribute__((ext_vector_type(8))) short;   // 8 bf16 in 4 VGPRs

__device__ __forceinline__ unsigned short f2bf(float x) {
  union { float f; uint32_t u; } v; v.f = x;
  uint32_t u = v.u;
  return (unsigned short)((u + 0x7FFFu + ((u >> 16) & 1u)) >> 16);  // RNE
}

__device__ __forceinline__ uint32_t cvtpk(float a, float b) {
  uint32_t r;
  asm("v_cvt_pk_bf16_f32 %0, %1, %2" : "=v"(r) : "v"(a), "v"(b));
  return r;
}

// async global->LDS, 16B per lane. lds ptr must be wave-uniform base; HW adds lane*16.
__device__ __forceinline__ void gload16(const void* g, void* l) {
  __builtin_amdgcn_global_load_lds(
      (const __attribute__((address_space(1))) void*)g,
      (__attribute__((address_space(3))) void*)l, 16, 0, 0);
}

#define BAR() do { asm volatile("" ::: "memory"); __builtin_amdgcn_s_barrier(); \
                   asm volatile("" ::: "memory"); } while (0)
#define VMC(N) asm volatile("s_waitcnt vmcnt(" #N ")" ::: "memory")

// ---------------- fused prep: cvt + W transposes + rope tables, ONE launch --------
__global__ __launch_bounds__(256)
void k_prep(const float* __restrict__ x,      unsigned short* __restrict__ xb,
            const float* __restrict__ Wqkv,   unsigned short* __restrict__ WqkvT,
            const float* __restrict__ Wproj,  unsigned short* __restrict__ WprojT,
            float* __restrict__ cosT, float* __restrict__ sinT) {
  __shared__ float tile[32][33];
  const int blk = blockIdx.x;
  const int tid = threadIdx.x;
  if (blk < 8192) {                       // ---- cvt bf16
    int i = (blk * 256 + tid) * 4;
    float4 v = *(const float4*)(x + i);
    ushort4 o;
    o.x = f2bf(v.x); o.y = f2bf(v.y); o.z = f2bf(v.z); o.w = f2bf(v.w);
    *(ushort4*)(xb + i) = o;
    return;
  }
  const int tx = tid & 31, ty = tid >> 5;
  if (blk < 12288) {                      // ---- W transposes
    const float* W; unsigned short* WT; int N, local;
    if (blk < 11264) { W = Wqkv;  WT = WqkvT;  N = 3*C_; local = blk - 8192; }
    else             { W = Wproj; WT = WprojT; N = C_;   local = blk - 11264; }
    const int NT = N / 32;
    const int bx = local % NT, by = local / NT;
    #pragma unroll
    for (int i = 0; i < 32; i += 8)
      tile[ty + i][tx] = W[(size_t)(by*32 + ty + i) * N + bx*32 + tx];
    __syncthreads();
    #pragma unroll
    for (int i = 0; i < 32; i += 8)
      WT[(size_t)(bx*32 + ty + i) * C_ + by*32 + tx] = f2bf(tile[tx][ty + i]);
    return;
  }
  {                                       // ---- rope tables
    int t = (blk - 12288) * 8 + ty;
    float inv = expf(-(float)tx * (9.210340371976184f / 32.0f));
    float f = (float)t * inv;
    cosT[t*32 + tx] = cosf(f);
    sinT[t*32 + tx] = sinf(f);
  }
}

// ---- GEMM: 256x256 tile, BK=64, 8 waves (2Mx4N, per-wave 128x64), 8-phase ----
// Shape rationale: per-wave 64x64 (R8) = 16 b128-reads/16 MFMA -> LDS-BW caps
// MfmaUtil at ~30% (measured 22.6). Per-wave 128x64 = 24 reads/64 MFMA -> ~60%.
// Schedule (race-proven via register-consumption ordering; see phase comments):
//   P1: ds A(qr0)+B(qc0); stage t+1:A1 -> dead buf  | BAR | 16 MFMA | BAR
//   P2: ds B(qc1)                                    | BAR | 16 MFMA | BAR
//   P3: ds A(qr1); stage t+2:B0 -> cur (B reads done)| BAR | 16 MFMA | BAR
//   P4: stage t+2:{B1,A0} -> cur (A reads done)      | BAR | 16 MFMA | VMC(6) | BAR
// VMC(6) ledger: in-flight = t+1{B0,B1,A0,A1}=8 + t+2{B0,B1,A0}=6 = 14; drains
// the oldest 8 = all of t+1 -> every unit gets >=3 phases of HBM cover.
// A: [M][K] bf16 row-major. BT: [N][K] bf16 (B^T, K-contiguous). LDS 128 KB.
template<int N, int K, int EPI>
__global__ __launch_bounds__(512)
void k_gemm8(const unsigned short* __restrict__ Ag,
             const unsigned short* __restrict__ BT,
             const float* __restrict__ bias,
             const float* __restrict__ cosT,
             const float* __restrict__ sinT,
             unsigned short* __restrict__ Qh,
             unsigned short* __restrict__ Kh,
             unsigned short* __restrict__ VhT,
             float* __restrict__ outF) {
  // [buf][half][128*64] per operand
  __shared__ alignas(16) unsigned short Asf[2*2*8192];
  __shared__ alignas(16) unsigned short Bsf[2*2*8192];
  const int tid  = threadIdx.x;
  const int lane = tid & 63;
  const int wv   = tid >> 6;               // 0..7
  const int wr   = wv >> 2, wc = wv & 3;   // 2M x 4N
  const int l15  = lane & 15, l4 = lane >> 4;
  // XCD-aware bijective swizzle (grid % 8 == 0), m-fastest within chunk.
  const int id  = ((int)blockIdx.x & 7) * ((int)gridDim.x >> 3) + ((int)blockIdx.x >> 3);
  const int m0  = (id % 32) * 256;         // M/256 = 32 m-tiles
  const int n0  = (id / 32) * 256;

  f32x4  acc[2][2][4][2] = {};             // [qr][qc][mi][ni]
  bf16x8 af[4][2], bq0[2][2], bq1[2][2];   // A frags (qr-current), B frags qc0/qc1

  // ---- hoisted LDS read pointers; granule g = (ks*4+l4) ^ (row&7), row&7==l15&7 ----
  const int g0 = l4 ^ (l15 & 7);
  const int g1 = (4 + l4) ^ (l15 & 7);
  const unsigned short* a0k0 = Asf + (0*2 + wr)*8192 + l15*64 + g0*8;
  const unsigned short* a0k1 = Asf + (0*2 + wr)*8192 + l15*64 + g1*8;
  const unsigned short* a1k0 = Asf + (1*2 + wr)*8192 + l15*64 + g0*8;
  const unsigned short* a1k1 = Asf + (1*2 + wr)*8192 + l15*64 + g1*8;
  const int bRow = (wc & 1)*64 + l15;
  const unsigned short* b0k0 = Bsf + (0*2 + (wc>>1))*8192 + bRow*64 + g0*8;
  const unsigned short* b0k1 = Bsf + (0*2 + (wc>>1))*8192 + bRow*64 + g1*8;
  const unsigned short* b1k0 = Bsf + (1*2 + (wc>>1))*8192 + bRow*64 + g0*8;
  const unsigned short* b1k1 = Bsf + (1*2 + (wc>>1))*8192 + bRow*64 + g1*8;

  // ---- staging: unit = one 128-row half of one operand of one K-tile (2 loads) ----
  const int vrow  = tid >> 3;                          // 0..63
  const int vg    = (tid & 7) ^ (vrow & 7);            // slot ^ f(row), j-invariant
  const int vbase = vrow*K + vg*8;
  const int ldsW  = wv*512;                            // wave dest within 64-row chunk

#define STG_A(BUF, T, HALF) do { \
  const unsigned short* _s = Ag + (size_t)(m0 + (HALF)*128)*K + (T)*64 + vbase; \
  unsigned short* _d = Asf + ((BUF)*2 + (HALF))*8192 + ldsW; \
  gload16(_s, _d); gload16(_s + 64*K, _d + 4096); \
} while (0)

#define STG_B(BUF, T, HALF) do { \
  const unsigned short* _s = BT + (size_t)(n0 + (HALF)*128)*K + (T)*64 + vbase; \
  unsigned short* _d = Bsf + ((BUF)*2 + (HALF))*8192 + ldsW; \
  gload16(_s, _d); gload16(_s + 64*K, _d + 4096); \
} while (0)

#define LDA(BUF, QR) do { \
  const unsigned short* _p0 = (BUF) ? a1k0 : a0k0; \
  const unsigned short* _p1 = (BUF) ? a1k1 : a0k1; \
  _Pragma("unroll") for (int mi = 0; mi < 4; ++mi) { \
    af[mi][0] = *(const bf16x8*)(_p0 + (QR)*4096 + mi*1024); \
    af[mi][1] = *(const bf16x8*)(_p1 + (QR)*4096 + mi*1024); } \
} while (0)

#define LDB(BUF, QC, BQ) do { \
  const unsigned short* _p0 = (BUF) ? b1k0 : b0k0; \
  const unsigned short* _p1 = (BUF) ? b1k1 : b0k1; \
  _Pragma("unroll") for (int ni = 0; ni < 2; ++ni) { \
    BQ[ni][0] = *(const bf16x8*)(_p0 + (QC)*2048 + ni*1024); \
    BQ[ni][1] = *(const bf16x8*)(_p1 + (QC)*2048 + ni*1024); } \
} while (0)

#define MMQ(QR, QC, BQ) do { \
  __builtin_amdgcn_s_setprio(1); \
  _Pragma("unroll") for (int ks = 0; ks < 2; ++ks) \
  _Pragma("unroll") for (int mi = 0; mi < 4; ++mi) \
  _Pragma("unroll") for (int ni = 0; ni < 2; ++ni) \
    acc[QR][QC][mi][ni] = __builtin_amdgcn_mfma_f32_16x16x32_bf16( \
        af[mi][ks], BQ[ni][ks], acc[QR][QC][mi][ni], 0, 0, 0); \
  __builtin_amdgcn_s_setprio(0); \
} while (0)

#define TILE(BUF, T) do { \
  /* P1: quad(0,0) */ \
  LDA(BUF, 0); LDB(BUF, 0, bq0); \
  if ((T) + 1 < KT_) STG_A(BUF^1, (T)+1, 1); \
  BAR(); MMQ(0, 0, bq0); BAR(); \
  /* P2: quad(0,1) */ \
  LDB(BUF, 1, bq1); \
  BAR(); MMQ(0, 1, bq1); BAR(); \
  /* P3: quad(1,0) — all B reads of this buf consumed (P2 regs) => B stage safe */ \
  LDA(BUF, 1); \
  if ((T) + 2 < KT_) STG_B(BUF, (T)+2, 0); \
  BAR(); MMQ(1, 0, bq0); BAR(); \
  /* P4: quad(1,1) — all A reads consumed (P3 regs) => A stage safe */ \
  if ((T) + 2 < KT_) { STG_B(BUF, (T)+2, 1); STG_A(BUF, (T)+2, 0); } \
  BAR(); MMQ(1, 1, bq1); \
  if ((T) + 2 < KT_)      { VMC(6); } \
  else if ((T) + 1 < KT_) { VMC(0); } \
  BAR(); \
} while (0)

  // prologue: t0 complete (8 loads) + t1:{B0,B1,A0} (6) -> VMC(6) drains t0
  STG_A(0, 0, 0); STG_A(0, 0, 1); STG_B(0, 0, 0); STG_B(0, 0, 1);
  STG_B(1, 1, 0); STG_B(1, 1, 1); STG_A(1, 1, 0);
  VMC(6);
  BAR();

  #pragma unroll 1
  for (int i = 0; i < KT_/2; ++i) {
    TILE(0, 2*i);
    TILE(1, 2*i + 1);
  }
  VMC(0);

#undef STG_A
#undef STG_B
#undef LDA
#undef LDB
#undef MMQ
#undef TILE

  // epilogue. D layout: col = lane&15, row = (lane>>4)*4 + j  [m89/m91]
  if (EPI == 0) {
    const int ncol = n0 + wc*64;            // wave spans exactly one (part, head)
    const int part = ncol >> 10;            // 0=Q 1=K 2=V
    const int hid  = (ncol & 1023) >> 6;
    unsigned short* dstQK = (part == 0) ? Qh : Kh;
    #pragma unroll
    for (int qr = 0; qr < 2; ++qr)
      #pragma unroll
      for (int mi = 0; mi < 4; ++mi)
        #pragma unroll
        for (int j = 0; j < 4; ++j) {
          int row = m0 + wr*128 + qr*64 + mi*16 + l4*4 + j;
          int bb = row >> 11, tt = row & 2047;
          if (part < 2) {
            size_t base = ((size_t)((bb*NH_ + hid) * T_ + tt)) * HD_;
            #pragma unroll
            for (int ni = 0; ni < 2; ++ni) {
              int d = ni*16 + l15;
              float a1 = acc[qr][0][mi][ni][j] + bias[ncol + d];
              float a2 = acc[qr][1][mi][ni][j] + bias[ncol + d + 32];
              float cv = cosT[tt*32 + d], sv = sinT[tt*32 + d];
              float o1 = a1*cv - a2*sv;
              float o2 = a2*cv + a1*sv;
              // Q: fold 1/sqrt(64)*log2(e) -> attention works in exp2 domain
              if (part == 0) { o1 *= 0.18033688011112042f; o2 *= 0.18033688011112042f; }
              dstQK[base + d]      = f2bf(o1);
              dstQK[base + d + 32] = f2bf(o2);
            }
          } else {
            #pragma unroll
            for (int qc = 0; qc < 2; ++qc)
              #pragma unroll
              for (int ni = 0; ni < 2; ++ni) {
                int d = qc*32 + ni*16 + l15;
                float av = acc[qr][qc][mi][ni][j] + bias[ncol + d];
                VhT[((size_t)((bb*NH_ + hid) * HD_ + d)) * T_ + tt] = f2bf(av);
              }
          }
        }
  } else {
    #pragma unroll
    for (int qr = 0; qr < 2; ++qr)
      #pragma unroll
      for (int qc = 0; qc < 2; ++qc)
        #pragma unroll
        for (int mi = 0; mi < 4; ++mi)
          #pragma unroll
          for (int ni = 0; ni < 2; ++ni)
            #pragma unroll
            for (int j = 0; j < 4; ++j) {
              int row = m0 + wr*128 + qr*64 + mi*16 + l4*4 + j;
              int col = n0 + wc*64 + qc*32 + ni*16 + l15;
              outF[(size_t)row * N + col] = acc[qr][qc][mi][ni][j] + bias[col];
            }
  }
}

// ---------------- flash attention (causal), 32x32 MFMA, swapped QK^T ----------------
// (R8/R15-verified version — best measured.) Qh pre-scaled by 0.125*log2(e);
// softmax via exp2. 1D grid: bh = blk&63, qb = 15-(blk>>6). Lane l owns q-row (l&31).
__global__ __launch_bounds__(256, 3)
void k_attn(const unsigned short* __restrict__ Qh,
            const unsigned short* __restrict__ Kh,
            const unsigned short* __restrict__ VhT,
            unsigned short* __restrict__ Y) {
  __shared__ alignas(16) unsigned short Ks[2][64*64];   // [key][d], XOR-swizzled 16B granules
  __shared__ alignas(16) unsigned short Vs[2][64*64];   // [d][key], XOR-swizzled
  const int tid  = threadIdx.x;
  const int lane = tid & 63;
  const int wv   = tid >> 6;
  const int l31  = lane & 31;
  const int h    = lane >> 5;
  const int bh   = blockIdx.x & 63;
  const int qb   = 15 - (blockIdx.x >> 6);          // balanced qb spread per CU
  const int r32  = qb*128 + wv*32;                  // wave's first q-row
  const int nt   = 2*qb + 2;
  const int qg   = r32 + l31;                       // this lane's q-row (global)

  // Q B-frags: qf[i] = Q[qg][d = i*16 + h*8 + e]
  bf16x8 qf[4];
  #pragma unroll
  for (int i = 0; i < 4; ++i)
    qf[i] = *(const bf16x8*)(Qh + ((size_t)(bh*T_ + qg))*HD_ + i*16 + h*8);

  float m_r = -1e30f, l_r = 0.f;
  f32x16 o[2] = {};   // o[dblk][r]: O[q = qg][d = dblk*32 + (r&3)+8*(r>>2)+4*h]

  auto stage = [&](int buf, int jt) {
    #pragma unroll
    for (int it = 0; it < 2; ++it) {
      int idx = it*256 + wv*64 + lane;
      int row = idx >> 3, slot = idx & 7;
      int g   = slot ^ (row & 7);
      gload16(Kh  + ((size_t)(bh*T_ + jt*64 + row))*HD_ + g*8,
              (void*)(Ks[buf] + (it*256 + wv*64)*8));
      gload16(VhT + ((size_t)(bh*HD_ + row))*T_ + jt*64 + g*8,
              (void*)(Vs[buf] + (it*256 + wv*64)*8));
    }
  };

  stage(0, 0);
  int cur = 0;

  for (int jt = 0; jt < nt; ++jt) {
    if (jt + 1 < nt) {
      stage(cur ^ 1, jt + 1);
      VMC(4);
    } else {
      VMC(0);
    }
    BAR();

    if (jt*64 <= r32 + 31) {     // wave-uniform skip of fully-masked tiles
      // S^T tiles: s[kb][r] = S[key = jt*64+kb*32+(r&3)+8*(r>>2)+4*h][q = qg]
      f32x16 s[2] = {f32x16{0}, f32x16{0}};
      __builtin_amdgcn_s_setprio(1);
      #pragma unroll
      for (int kb = 0; kb < 2; ++kb)
        #pragma unroll
        for (int i = 0; i < 4; ++i) {
          int r = kb*32 + l31;
          int g = (2*i + h) ^ (r & 7);
          bf16x8 kf = *(const bf16x8*)(Ks[cur] + r*64 + g*8);
          s[kb] = __builtin_amdgcn_mfma_f32_32x32x16_bf16(kf, qf[i], s[kb], 0, 0, 0);
        }
      __builtin_amdgcn_s_setprio(0);

      // extract + causal mask (diagonal tiles only)
      float p[2][16];
      const bool diag = (jt + 1)*64 > r32;
      #pragma unroll
      for (int kb = 0; kb < 2; ++kb)
        #pragma unroll
        for (int r = 0; r < 16; ++r) {
          float v = s[kb][r];
          if (diag) {
            int key = jt*64 + kb*32 + (r & 3) + 8*(r >> 2) + 4*h;
            v = (key > qg) ? -1e30f : v;
          }
          p[kb][r] = v;
        }

      // row max: in-lane tree + one cross-half swap
      float mx[16];
      #pragma unroll
      for (int r = 0; r < 16; ++r) mx[r] = fmaxf(p[0][r], p[1][r]);
      #pragma unroll
      for (int st = 8; st > 0; st >>= 1)
        #pragma unroll
        for (int r = 0; r < 8; ++r)
          if (r < st) mx[r] = fmaxf(mx[r], mx[r + st]);
      float tm = fmaxf(mx[0], __shfl_xor(mx[0], 32));

      // defer-max (T13): only rescale when tile max outgrows running max by >8
      if (!__all(tm <= m_r + 8.0f)) {
        float mn = fmaxf(m_r, tm);
        float scale = exp2f(m_r - mn);
        m_r = mn;
        l_r *= scale;
        #pragma unroll
        for (int dblk = 0; dblk < 2; ++dblk)
          #pragma unroll
          for (int r = 0; r < 16; ++r)
            o[dblk][r] *= scale;
      }

      #pragma unroll
      for (int kb = 0; kb < 2; ++kb)
        #pragma unroll
        for (int r = 0; r < 16; ++r)
          p[kb][r] = exp2f(p[kb][r] - m_r);

      float sm[16];
      #pragma unroll
      for (int r = 0; r < 16; ++r) sm[r] = p[0][r] + p[1][r];
      #pragma unroll
      for (int st = 8; st > 0; st >>= 1)
        #pragma unroll
        for (int r = 0; r < 8; ++r)
          if (r < st) sm[r] += sm[r + st];
      l_r += sm[0] + __shfl_xor(sm[0], 32);

      // PV per key-block: P B-frags via cvt_pk + ONE swap per pair (pre-selected).
      #pragma unroll
      for (int kb = 0; kb < 2; ++kb) {
        uint32_t a01 = cvtpk(p[kb][0],  p[kb][1]);
        uint32_t a23 = cvtpk(p[kb][2],  p[kb][3]);
        uint32_t a45 = cvtpk(p[kb][4],  p[kb][5]);
        uint32_t a67 = cvtpk(p[kb][6],  p[kb][7]);
        uint32_t b01 = cvtpk(p[kb][8],  p[kb][9]);
        uint32_t b23 = cvtpk(p[kb][10], p[kb][11]);
        uint32_t b45 = cvtpk(p[kb][12], p[kb][13]);
        uint32_t b67 = cvtpk(p[kb][14], p[kb][15]);
        uint32_t s1 = h ? a01 : a45, s2 = h ? a23 : a67;   // send what partner needs
        uint32_t s3 = h ? b01 : b45, s4 = h ? b23 : b67;
        uint32_t x1 = __shfl_xor(s1, 32), x2 = __shfl_xor(s2, 32);
        uint32_t x3 = __shfl_xor(s3, 32), x4 = __shfl_xor(s4, 32);
        union { bf16x8 v; uint32_t d[4]; } f0, f1;
        f0.d[0] = h ? x1 : a01;  f0.d[1] = h ? x2 : a23;
        f0.d[2] = h ? a45 : x1;  f0.d[3] = h ? a67 : x2;
        f1.d[0] = h ? x3 : b01;  f1.d[1] = h ? x4 : b23;
        f1.d[2] = h ? b45 : x3;  f1.d[3] = h ? b67 : x4;

        __builtin_amdgcn_s_setprio(1);
        #pragma unroll
        for (int koff = 0; koff < 2; ++koff) {
          bf16x8 pf = koff ? f1.v : f0.v;
          #pragma unroll
          for (int dblk = 0; dblk < 2; ++dblk) {
            int rv = dblk*32 + l31;
            int gv = (kb*4 + koff*2 + h) ^ (rv & 7);
            bf16x8 vf = *(const bf16x8*)(Vs[cur] + rv*64 + gv*8);
            // A = V^T (row=d, lane-local l31), B = P (col=q, lane-local l31)
            o[dblk] = __builtin_amdgcn_mfma_f32_32x32x16_bf16(vf, pf, o[dblk], 0, 0, 0);
          }
        }
        __builtin_amdgcn_s_setprio(0);
      }
    }

    BAR();   // raw: all LDS reads of this tile were consumed above
    cur ^= 1;
  }

  // epilogue: lane-local normalize, packed ushort4 stores
  int b = bh >> 4, hd = bh & 15;
  float rinv = 1.0f / l_r;
  unsigned short* yrow = Y + ((size_t)(b*T_ + r32 + l31))*C_ + hd*64;
  #pragma unroll
  for (int dblk = 0; dblk < 2; ++dblk)
    #pragma unroll
    for (int g2 = 0; g2 < 4; ++g2) {
      ushort4 o4;
      o4.x = f2bf(o[dblk][g2*4 + 0] * rinv);
      o4.y = f2bf(o[dblk][g2*4 + 1] * rinv);
      o4.z = f2bf(o[dblk][g2*4 + 2] * rinv);
      o4.w = f2bf(o[dblk][g2*4 + 3] * rinv);
      *(ushort4*)(yrow + dblk*32 + g2*8 + 4*h) = o4;
    }
}

// ---------------- host ----------------

extern "C" void kernel_launch(void* const* d_in, const int* in_sizes, int n_in,
                              void* d_out, int out_size, void* d_ws, size_t ws_size,
                              hipStream_t stream) {
  const float* x      = (const float*)d_in[0];
  const float* W_qkv  = (const float*)d_in[1];
  const float* b_qkv  = (const float*)d_in[2];
  const float* W_proj = (const float*)d_in[3];
  const float* b_proj = (const float*)d_in[4];
  float* out = (float*)d_out;

  char* ws = (char*)d_ws;
  size_t off = 0;
  auto alloc = [&](size_t bytes) {
    void* p = ws + off; off += (bytes + 255) & ~(size_t)255; return p;
  };
  unsigned short* xb     = (unsigned short*)alloc((size_t)M_ * C_ * 2);  // also reused as Y
  unsigned short* WqkvT  = (unsigned short*)alloc((size_t)3 * C_ * C_ * 2);
  unsigned short* WprojT = (unsigned short*)alloc((size_t)C_ * C_ * 2);
  unsigned short* Qh     = (unsigned short*)alloc((size_t)M_ * C_ * 2);
  unsigned short* Kh     = (unsigned short*)alloc((size_t)M_ * C_ * 2);
  unsigned short* VhT    = (unsigned short*)alloc((size_t)M_ * C_ * 2);
  float* cosT = (float*)alloc((size_t)T_ * 32 * 4);
  float* sinT = (float*)alloc((size_t)T_ * 32 * 4);
  unsigned short* Y = xb;   // xb dead after QKV GEMM; attention output aliases it

  // fused prep: 8192 cvt + 3072 qkvT + 1024 projT + 256 rope = 12544 blocks
  k_prep<<<dim3(12544), 256, 0, stream>>>(x, xb, W_qkv, WqkvT, W_proj, WprojT,
                                          cosT, sinT);

  // QKV: 32 m-tiles x 12 n-tiles = 384 blocks of 512 threads
  k_gemm8<3*C_, C_, 0><<<dim3(384), 512, 0, stream>>>(
      xb, WqkvT, b_qkv, cosT, sinT, Qh, Kh, VhT, nullptr);

  // attn: QBLK=128, 4 waves/block; 16 qb x 64 bh = 1024 blocks
  k_attn<<<dim3(T_/128 * BH_), 256, 0, stream>>>(Qh, Kh, VhT, Y);

  // proj: 32 x 4 = 128 blocks of 512 threads
  k_gemm8<C_, C_, 1><<<dim3(128), 512, 0, stream>>>(
      Y, WprojT, b_proj, nullptr, nullptr, nullptr, nullptr, nullptr, out);
}

// Round 17
// 194.641 us; speedup vs baseline: 1.2816x; 1.2816x over previous
//
#include <hip/hip_runtime.h>
#include <stdint.h>

#define B_  4
#define T_  2048
#define C_  1024
#define NH_ 16
#define HD_ 64
#define BH_ (B_*NH_)   // 64
#define M_  (B_*T_)    // 8192

using f32x4  = __attribute__((ext_vector_type(4))) float;
using f32x16 = __attribute__((ext_vector_type(16))) float;
using bf16x8 = __attribute__((ext_vector_type(8))) short;   // 8 bf16 in 4 VGPRs

__device__ __forceinline__ unsigned short f2bf(float x) {
  union { float f; uint32_t u; } v; v.f = x;
  uint32_t u = v.u;
  return (unsigned short)((u + 0x7FFFu + ((u >> 16) & 1u)) >> 16);  // RNE
}

__device__ __forceinline__ uint32_t cvtpk(float a, float b) {
  uint32_t r;
  asm("v_cvt_pk_bf16_f32 %0, %1, %2" : "=v"(r) : "v"(a), "v"(b));
  return r;
}

// async global->LDS, 16B per lane. lds ptr must be wave-uniform base; HW adds lane*16.
__device__ __forceinline__ void gload16(const void* g, void* l) {
  __builtin_amdgcn_global_load_lds(
      (const __attribute__((address_space(1))) void*)g,
      (__attribute__((address_space(3))) void*)l, 16, 0, 0);
}

#define BAR() do { asm volatile("" ::: "memory"); __builtin_amdgcn_s_barrier(); \
                   asm volatile("" ::: "memory"); } while (0)
#define VMC(N) asm volatile("s_waitcnt vmcnt(" #N ")" ::: "memory")

// ---------------- fused prep: cvt + W transposes + rope tables, ONE launch --------
// Block ranges (all 256 threads):
//   [0, 8192)            : x f32 -> xb bf16 (1024 elems/block, float4)
//   [8192, 8192+3072)    : W_qkv [K][N] -> WqkvT [N][K] bf16 (32x32 tiles, 96 x 32)
//   [11264, 11264+1024)  : W_proj -> WprojT (32 x 32)
//   [12288, 12288+256)   : rope cos/sin tables (8 t-rows/block)
__global__ __launch_bounds__(256)
void k_prep(const float* __restrict__ x,      unsigned short* __restrict__ xb,
            const float* __restrict__ Wqkv,   unsigned short* __restrict__ WqkvT,
            const float* __restrict__ Wproj,  unsigned short* __restrict__ WprojT,
            float* __restrict__ cosT, float* __restrict__ sinT) {
  __shared__ float tile[32][33];
  const int blk = blockIdx.x;
  const int tid = threadIdx.x;
  if (blk < 8192) {                       // ---- cvt bf16
    int i = (blk * 256 + tid) * 4;
    float4 v = *(const float4*)(x + i);
    ushort4 o;
    o.x = f2bf(v.x); o.y = f2bf(v.y); o.z = f2bf(v.z); o.w = f2bf(v.w);
    *(ushort4*)(xb + i) = o;
    return;
  }
  const int tx = tid & 31, ty = tid >> 5; // (32,8) shape for the rest
  if (blk < 12288) {                      // ---- W transposes
    const float* W; unsigned short* WT; int N, local;
    if (blk < 11264) { W = Wqkv;  WT = WqkvT;  N = 3*C_; local = blk - 8192; }
    else             { W = Wproj; WT = WprojT; N = C_;   local = blk - 11264; }
    const int NT = N / 32;
    const int bx = local % NT, by = local / NT;
    #pragma unroll
    for (int i = 0; i < 32; i += 8)
      tile[ty + i][tx] = W[(size_t)(by*32 + ty + i) * N + bx*32 + tx];
    __syncthreads();
    #pragma unroll
    for (int i = 0; i < 32; i += 8)
      WT[(size_t)(bx*32 + ty + i) * C_ + by*32 + tx] = f2bf(tile[tx][ty + i]);
    return;
  }
  {                                       // ---- rope tables
    int t = (blk - 12288) * 8 + ty;
    float inv = expf(-(float)tx * (9.210340371976184f / 32.0f));
    float f = (float)t * inv;
    cosT[t*32 + tx] = cosf(f);
    sinT[t*32 + tx] = sinf(f);
  }
}

// ---- GEMM (R8-verified best): 128x128, BK=64, 4 waves, dbuf + vmcnt(8), hoisted ----
// A: [M][K] bf16 row-major. BT: [N][K] bf16 (B^T, K-contiguous).
template<int N, int K, int EPI>
__global__ __launch_bounds__(256)
void k_gemm(const unsigned short* __restrict__ Ag,
            const unsigned short* __restrict__ BT,
            const float* __restrict__ bias,
            const float* __restrict__ cosT,
            const float* __restrict__ sinT,
            unsigned short* __restrict__ Qh,
            unsigned short* __restrict__ Kh,
            unsigned short* __restrict__ VhT,
            float* __restrict__ outF) {
  __shared__ alignas(16) unsigned short As[2][128*64];
  __shared__ alignas(16) unsigned short Bs[2][128*64];
  const int tid  = threadIdx.x;
  const int lane = tid & 63;
  const int wv   = tid >> 6;
  const int wm   = wv >> 1, wn = wv & 1;
  const int l15  = lane & 15, l4 = lane >> 4;
  // XCD-aware bijective swizzle (grid % 8 == 0), n-fastest within chunk.
  const int NT  = N / 128;
  const int id  = ((int)blockIdx.x & 7) * ((int)gridDim.x >> 3) + ((int)blockIdx.x >> 3);
  const int m0  = (id / NT) * 128;
  const int n0  = (id % NT) * 128;

  f32x4 acc[4][4] = {};

  // ---- hoisted LDS read pointers (K-loop invariant; row&7 == l15&7) ----
  const int g0 = l4 ^ (l15 & 7);          // ks=0 granule
  const int g1 = (4 + l4) ^ (l15 & 7);    // ks=1 granule
  const int rowA = wm*64 + l15, rowB = wn*64 + l15;
  const unsigned short* aRd0k0 = &As[0][rowA*64 + g0*8];
  const unsigned short* aRd0k1 = &As[0][rowA*64 + g1*8];
  const unsigned short* aRd1k0 = &As[1][rowA*64 + g0*8];
  const unsigned short* aRd1k1 = &As[1][rowA*64 + g1*8];
  const unsigned short* bRd0k0 = &Bs[0][rowB*64 + g0*8];
  const unsigned short* bRd0k1 = &Bs[0][rowB*64 + g1*8];
  const unsigned short* bRd1k0 = &Bs[1][rowB*64 + g0*8];
  const unsigned short* bRd1k1 = &Bs[1][rowB*64 + g1*8];

  // ---- hoisted staging offsets ----
  const int srow = wv*8 + (lane >> 3);                 // row within 32-row unit
  const int sg   = (lane & 7) ^ ((lane >> 3) & 7);     // granule (it/wv-invariant)
  const int voff = srow*K + sg*8;                      // per-lane, A and B identical
  const int aUni = m0*K, bUni = n0*K;
  const int ldsD = wv*512;                             // wave's LDS dest (elements)

#define STG(BUF, KT) do { \
  const int _u = (KT)*64; \
  _Pragma("unroll") for (int it = 0; it < 4; ++it) { \
    gload16(Ag + (aUni + it*(32*K) + _u) + voff, (void*)(&As[BUF][it*2048 + ldsD])); \
    gload16(BT + (bUni + it*(32*K) + _u) + voff, (void*)(&Bs[BUF][it*2048 + ldsD])); \
  } \
} while (0)

#define CMP(AK0, AK1, BK0, BK1) do { \
  bf16x8 afr[4][2], bfr[4][2]; \
  _Pragma("unroll") for (int mi = 0; mi < 4; ++mi) { \
    afr[mi][0] = *(const bf16x8*)((AK0) + mi*1024); \
    afr[mi][1] = *(const bf16x8*)((AK1) + mi*1024); \
    bfr[mi][0] = *(const bf16x8*)((BK0) + mi*1024); \
    bfr[mi][1] = *(const bf16x8*)((BK1) + mi*1024); \
  } \
  __builtin_amdgcn_s_setprio(1); \
  _Pragma("unroll") for (int ks = 0; ks < 2; ++ks) \
  _Pragma("unroll") for (int mi = 0; mi < 4; ++mi) \
  _Pragma("unroll") for (int ni = 0; ni < 4; ++ni) \
    acc[mi][ni] = __builtin_amdgcn_mfma_f32_16x16x32_bf16( \
        afr[mi][ks], bfr[ni][ks], acc[mi][ni], 0, 0, 0); \
  __builtin_amdgcn_s_setprio(0); \
} while (0)

  STG(0, 0);
  #pragma unroll 1
  for (int i = 0; i < K/128; ++i) {
    STG(1, 2*i + 1);            // prefetch odd tile into buf1
    VMC(8);                     // buf0's 8 loads done; prefetch in flight
    BAR();
    CMP(aRd0k0, aRd0k1, bRd0k0, bRd0k1);
    BAR();
    if (i + 1 < K/128) {
      STG(0, 2*i + 2);          // prefetch next even tile into buf0
      VMC(8);
    } else {
      VMC(0);
    }
    BAR();
    CMP(aRd1k0, aRd1k1, bRd1k0, bRd1k1);
    BAR();
  }
#undef STG
#undef CMP

  // epilogue. D layout: col = lane&15, row = (lane>>4)*4 + j  [m89/m91]
  if (EPI == 0) {
    const int ncol = n0 + wn*64;            // wave spans exactly one (part, head)
    const int part = ncol >> 10;            // 0=Q 1=K 2=V
    const int hid  = (ncol & 1023) >> 6;
    unsigned short* dstQK = (part == 0) ? Qh : Kh;
    #pragma unroll
    for (int mi = 0; mi < 4; ++mi) {
      #pragma unroll
      for (int j = 0; j < 4; ++j) {
        int row = m0 + wm*64 + mi*16 + l4*4 + j;
        int bb = row >> 11, tt = row & 2047;
        if (part < 2) {
          size_t base = ((size_t)((bb*NH_ + hid) * T_ + tt)) * HD_;
          #pragma unroll
          for (int ni = 0; ni < 2; ++ni) {
            int d = ni*16 + l15;
            float a1 = acc[mi][ni][j]     + bias[ncol + d];
            float a2 = acc[mi][ni + 2][j] + bias[ncol + d + 32];
            float cv = cosT[tt*32 + d], sv = sinT[tt*32 + d];
            float o1 = a1*cv - a2*sv;
            float o2 = a2*cv + a1*sv;
            // Q: fold 1/sqrt(64) * log2(e) so attention works in exp2 domain
            if (part == 0) { o1 *= 0.18033688011112042f; o2 *= 0.18033688011112042f; }
            dstQK[base + d]      = f2bf(o1);
            dstQK[base + d + 32] = f2bf(o2);
          }
        } else {
          #pragma unroll
          for (int ni = 0; ni < 4; ++ni) {
            int d = ni*16 + l15;
            float av = acc[mi][ni][j] + bias[ncol + d];
            VhT[((size_t)((bb*NH_ + hid) * HD_ + d)) * T_ + tt] = f2bf(av);
          }
        }
      }
    }
  } else {
    #pragma unroll
    for (int mi = 0; mi < 4; ++mi)
      #pragma unroll
      for (int ni = 0; ni < 4; ++ni)
        #pragma unroll
        for (int j = 0; j < 4; ++j) {
          int row = m0 + wm*64 + mi*16 + l4*4 + j;
          int col = n0 + wn*64 + ni*16 + l15;
          outF[(size_t)row * N + col] = acc[mi][ni][j] + bias[col];
        }
  }
}

// ---------------- flash attention (causal), 32x32 MFMA, swapped QK^T ----------------
// (R8/R15-verified version — best measured.) Qh pre-scaled by 0.125*log2(e);
// softmax via exp2. 1D grid: bh = blk&63, qb = 15-(blk>>6). Lane l owns q-row (l&31).
__global__ __launch_bounds__(256, 3)
void k_attn(const unsigned short* __restrict__ Qh,
            const unsigned short* __restrict__ Kh,
            const unsigned short* __restrict__ VhT,
            unsigned short* __restrict__ Y) {
  __shared__ alignas(16) unsigned short Ks[2][64*64];   // [key][d], XOR-swizzled 16B granules
  __shared__ alignas(16) unsigned short Vs[2][64*64];   // [d][key], XOR-swizzled
  const int tid  = threadIdx.x;
  const int lane = tid & 63;
  const int wv   = tid >> 6;
  const int l31  = lane & 31;
  const int h    = lane >> 5;
  const int bh   = blockIdx.x & 63;
  const int qb   = 15 - (blockIdx.x >> 6);          // balanced qb spread per CU
  const int r32  = qb*128 + wv*32;                  // wave's first q-row
  const int nt   = 2*qb + 2;
  const int qg   = r32 + l31;                       // this lane's q-row (global)

  // Q B-frags: qf[i] = Q[qg][d = i*16 + h*8 + e]
  bf16x8 qf[4];
  #pragma unroll
  for (int i = 0; i < 4; ++i)
    qf[i] = *(const bf16x8*)(Qh + ((size_t)(bh*T_ + qg))*HD_ + i*16 + h*8);

  float m_r = -1e30f, l_r = 0.f;
  f32x16 o[2] = {};   // o[dblk][r]: O[q = qg][d = dblk*32 + (r&3)+8*(r>>2)+4*h]

  auto stage = [&](int buf, int jt) {
    #pragma unroll
    for (int it = 0; it < 2; ++it) {
      int idx = it*256 + wv*64 + lane;
      int row = idx >> 3, slot = idx & 7;
      int g   = slot ^ (row & 7);
      gload16(Kh  + ((size_t)(bh*T_ + jt*64 + row))*HD_ + g*8,
              (void*)(Ks[buf] + (it*256 + wv*64)*8));
      gload16(VhT + ((size_t)(bh*HD_ + row))*T_ + jt*64 + g*8,
              (void*)(Vs[buf] + (it*256 + wv*64)*8));
    }
  };

  stage(0, 0);
  int cur = 0;

  for (int jt = 0; jt < nt; ++jt) {
    if (jt + 1 < nt) {
      stage(cur ^ 1, jt + 1);
      VMC(4);
    } else {
      VMC(0);
    }
    BAR();

    if (jt*64 <= r32 + 31) {     // wave-uniform skip of fully-masked tiles
      // S^T tiles: s[kb][r] = S[key = jt*64+kb*32+(r&3)+8*(r>>2)+4*h][q = qg]
      f32x16 s[2] = {f32x16{0}, f32x16{0}};
      __builtin_amdgcn_s_setprio(1);
      #pragma unroll
      for (int kb = 0; kb < 2; ++kb)
        #pragma unroll
        for (int i = 0; i < 4; ++i) {
          int r = kb*32 + l31;
          int g = (2*i + h) ^ (r & 7);
          bf16x8 kf = *(const bf16x8*)(Ks[cur] + r*64 + g*8);
          s[kb] = __builtin_amdgcn_mfma_f32_32x32x16_bf16(kf, qf[i], s[kb], 0, 0, 0);
        }
      __builtin_amdgcn_s_setprio(0);

      // extract + causal mask (diagonal tiles only)
      float p[2][16];
      const bool diag = (jt + 1)*64 > r32;
      #pragma unroll
      for (int kb = 0; kb < 2; ++kb)
        #pragma unroll
        for (int r = 0; r < 16; ++r) {
          float v = s[kb][r];
          if (diag) {
            int key = jt*64 + kb*32 + (r & 3) + 8*(r >> 2) + 4*h;
            v = (key > qg) ? -1e30f : v;
          }
          p[kb][r] = v;
        }

      // row max: in-lane tree + one cross-half swap
      float mx[16];
      #pragma unroll
      for (int r = 0; r < 16; ++r) mx[r] = fmaxf(p[0][r], p[1][r]);
      #pragma unroll
      for (int st = 8; st > 0; st >>= 1)
        #pragma unroll
        for (int r = 0; r < 8; ++r)
          if (r < st) mx[r] = fmaxf(mx[r], mx[r + st]);
      float tm = fmaxf(mx[0], __shfl_xor(mx[0], 32));

      // defer-max (T13): only rescale when tile max outgrows running max by >8
      if (!__all(tm <= m_r + 8.0f)) {
        float mn = fmaxf(m_r, tm);
        float scale = exp2f(m_r - mn);
        m_r = mn;
        l_r *= scale;
        #pragma unroll
        for (int dblk = 0; dblk < 2; ++dblk)
          #pragma unroll
          for (int r = 0; r < 16; ++r)
            o[dblk][r] *= scale;
      }

      #pragma unroll
      for (int kb = 0; kb < 2; ++kb)
        #pragma unroll
        for (int r = 0; r < 16; ++r)
          p[kb][r] = exp2f(p[kb][r] - m_r);

      float sm[16];
      #pragma unroll
      for (int r = 0; r < 16; ++r) sm[r] = p[0][r] + p[1][r];
      #pragma unroll
      for (int st = 8; st > 0; st >>= 1)
        #pragma unroll
        for (int r = 0; r < 8; ++r)
          if (r < st) sm[r] += sm[r + st];
      l_r += sm[0] + __shfl_xor(sm[0], 32);

      // PV per key-block: P B-frags via cvt_pk + ONE swap per pair (pre-selected).
      #pragma unroll
      for (int kb = 0; kb < 2; ++kb) {
        uint32_t a01 = cvtpk(p[kb][0],  p[kb][1]);
        uint32_t a23 = cvtpk(p[kb][2],  p[kb][3]);
        uint32_t a45 = cvtpk(p[kb][4],  p[kb][5]);
        uint32_t a67 = cvtpk(p[kb][6],  p[kb][7]);
        uint32_t b01 = cvtpk(p[kb][8],  p[kb][9]);
        uint32_t b23 = cvtpk(p[kb][10], p[kb][11]);
        uint32_t b45 = cvtpk(p[kb][12], p[kb][13]);
        uint32_t b67 = cvtpk(p[kb][14], p[kb][15]);
        uint32_t s1 = h ? a01 : a45, s2 = h ? a23 : a67;   // send what partner needs
        uint32_t s3 = h ? b01 : b45, s4 = h ? b23 : b67;
        uint32_t x1 = __shfl_xor(s1, 32), x2 = __shfl_xor(s2, 32);
        uint32_t x3 = __shfl_xor(s3, 32), x4 = __shfl_xor(s4, 32);
        union { bf16x8 v; uint32_t d[4]; } f0, f1;
        f0.d[0] = h ? x1 : a01;  f0.d[1] = h ? x2 : a23;
        f0.d[2] = h ? a45 : x1;  f0.d[3] = h ? a67 : x2;
        f1.d[0] = h ? x3 : b01;  f1.d[1] = h ? x4 : b23;
        f1.d[2] = h ? b45 : x3;  f1.d[3] = h ? b67 : x4;

        __builtin_amdgcn_s_setprio(1);
        #pragma unroll
        for (int koff = 0; koff < 2; ++koff) {
          bf16x8 pf = koff ? f1.v : f0.v;
          #pragma unroll
          for (int dblk = 0; dblk < 2; ++dblk) {
            int rv = dblk*32 + l31;
            int gv = (kb*4 + koff*2 + h) ^ (rv & 7);
            bf16x8 vf = *(const bf16x8*)(Vs[cur] + rv*64 + gv*8);
            // A = V^T (row=d, lane-local l31), B = P (col=q, lane-local l31)
            o[dblk] = __builtin_amdgcn_mfma_f32_32x32x16_bf16(vf, pf, o[dblk], 0, 0, 0);
          }
        }
        __builtin_amdgcn_s_setprio(0);
      }
    }

    BAR();   // raw: all LDS reads of this tile were consumed above
    cur ^= 1;
  }

  // epilogue: lane-local normalize, packed ushort4 stores
  int b = bh >> 4, hd = bh & 15;
  float rinv = 1.0f / l_r;
  unsigned short* yrow = Y + ((size_t)(b*T_ + r32 + l31))*C_ + hd*64;
  #pragma unroll
  for (int dblk = 0; dblk < 2; ++dblk)
    #pragma unroll
    for (int g2 = 0; g2 < 4; ++g2) {
      ushort4 o4;
      o4.x = f2bf(o[dblk][g2*4 + 0] * rinv);
      o4.y = f2bf(o[dblk][g2*4 + 1] * rinv);
      o4.z = f2bf(o[dblk][g2*4 + 2] * rinv);
      o4.w = f2bf(o[dblk][g2*4 + 3] * rinv);
      *(ushort4*)(yrow + dblk*32 + g2*8 + 4*h) = o4;
    }
}

// ---------------- host ----------------

extern "C" void kernel_launch(void* const* d_in, const int* in_sizes, int n_in,
                              void* d_out, int out_size, void* d_ws, size_t ws_size,
                              hipStream_t stream) {
  const float* x      = (const float*)d_in[0];
  const float* W_qkv  = (const float*)d_in[1];
  const float* b_qkv  = (const float*)d_in[2];
  const float* W_proj = (const float*)d_in[3];
  const float* b_proj = (const float*)d_in[4];
  float* out = (float*)d_out;

  char* ws = (char*)d_ws;
  size_t off = 0;
  auto alloc = [&](size_t bytes) {
    void* p = ws + off; off += (bytes + 255) & ~(size_t)255; return p;
  };
  unsigned short* xb     = (unsigned short*)alloc((size_t)M_ * C_ * 2);  // also reused as Y
  unsigned short* WqkvT  = (unsigned short*)alloc((size_t)3 * C_ * C_ * 2);
  unsigned short* WprojT = (unsigned short*)alloc((size_t)C_ * C_ * 2);
  unsigned short* Qh     = (unsigned short*)alloc((size_t)M_ * C_ * 2);
  unsigned short* Kh     = (unsigned short*)alloc((size_t)M_ * C_ * 2);
  unsigned short* VhT    = (unsigned short*)alloc((size_t)M_ * C_ * 2);
  float* cosT = (float*)alloc((size_t)T_ * 32 * 4);
  float* sinT = (float*)alloc((size_t)T_ * 32 * 4);
  unsigned short* Y = xb;   // xb dead after QKV GEMM; attention output aliases it

  // fused prep: 8192 cvt + 3072 qkvT + 1024 projT + 256 rope = 12544 blocks
  k_prep<<<dim3(12544), 256, 0, stream>>>(x, xb, W_qkv, WqkvT, W_proj, WprojT,
                                          cosT, sinT);

  // QKV: 64 m-tiles x 24 n-tiles = 1536 blocks (1D, XCD-swizzled in-kernel)
  k_gemm<3*C_, C_, 0><<<dim3(1536), 256, 0, stream>>>(
      xb, WqkvT, b_qkv, cosT, sinT, Qh, Kh, VhT, nullptr);

  // attn: QBLK=128, 4 waves/block; 16 qb x 64 bh = 1024 blocks
  k_attn<<<dim3(T_/128 * BH_), 256, 0, stream>>>(Qh, Kh, VhT, Y);

  // proj: 64 x 8 = 512 blocks
  k_gemm<C_, C_, 1><<<dim3(512), 256, 0, stream>>>(
      Y, WprojT, b_proj, nullptr, nullptr, nullptr, nullptr, nullptr, out);
}

// Round 18
// 193.149 us; speedup vs baseline: 1.2915x; 1.0077x over previous
//
#include <hip/hip_runtime.h>
#include <stdint.h>

#define B_  4
#define T_  2048
#define C_  1024
#define NH_ 16
#define HD_ 64
#define BH_ (B_*NH_)   // 64
#define M_  (B_*T_)    // 8192

using f32x4  = __attribute__((ext_vector_type(4))) float;
using f32x16 = __attribute__((ext_vector_type(16))) float;
using bf16x8 = __attribute__((ext_vector_type(8))) short;   // 8 bf16 in 4 VGPRs

__device__ __forceinline__ unsigned short f2bf(float x) {
  union { float f; uint32_t u; } v; v.f = x;
  uint32_t u = v.u;
  return (unsigned short)((u + 0x7FFFu + ((u >> 16) & 1u)) >> 16);  // RNE
}

__device__ __forceinline__ uint32_t cvtpk(float a, float b) {
  uint32_t r;
  asm("v_cvt_pk_bf16_f32 %0, %1, %2" : "=v"(r) : "v"(a), "v"(b));
  return r;
}

// async global->LDS, 16B per lane. lds ptr must be wave-uniform base; HW adds lane*16.
__device__ __forceinline__ void gload16(const void* g, void* l) {
  __builtin_amdgcn_global_load_lds(
      (const __attribute__((address_space(1))) void*)g,
      (__attribute__((address_space(3))) void*)l, 16, 0, 0);
}

#define BAR() do { asm volatile("" ::: "memory"); __builtin_amdgcn_s_barrier(); \
                   asm volatile("" ::: "memory"); } while (0)
#define VMC(N) asm volatile("s_waitcnt vmcnt(" #N ")" ::: "memory")

// ---------------- fused prep: cvt + W transposes + rope tables, ONE launch --------
__global__ __launch_bounds__(256)
void k_prep(const float* __restrict__ x,      unsigned short* __restrict__ xb,
            const float* __restrict__ Wqkv,   unsigned short* __restrict__ WqkvT,
            const float* __restrict__ Wproj,  unsigned short* __restrict__ WprojT,
            float* __restrict__ cosT, float* __restrict__ sinT) {
  __shared__ float tile[32][33];
  const int blk = blockIdx.x;
  const int tid = threadIdx.x;
  if (blk < 8192) {                       // ---- cvt bf16
    int i = (blk * 256 + tid) * 4;
    float4 v = *(const float4*)(x + i);
    ushort4 o;
    o.x = f2bf(v.x); o.y = f2bf(v.y); o.z = f2bf(v.z); o.w = f2bf(v.w);
    *(ushort4*)(xb + i) = o;
    return;
  }
  const int tx = tid & 31, ty = tid >> 5; // (32,8) shape for the rest
  if (blk < 12288) {                      // ---- W transposes
    const float* W; unsigned short* WT; int N, local;
    if (blk < 11264) { W = Wqkv;  WT = WqkvT;  N = 3*C_; local = blk - 8192; }
    else             { W = Wproj; WT = WprojT; N = C_;   local = blk - 11264; }
    const int NT = N / 32;
    const int bx = local % NT, by = local / NT;
    #pragma unroll
    for (int i = 0; i < 32; i += 8)
      tile[ty + i][tx] = W[(size_t)(by*32 + ty + i) * N + bx*32 + tx];
    __syncthreads();
    #pragma unroll
    for (int i = 0; i < 32; i += 8)
      WT[(size_t)(bx*32 + ty + i) * C_ + by*32 + tx] = f2bf(tile[tx][ty + i]);
    return;
  }
  {                                       // ---- rope tables
    int t = (blk - 12288) * 8 + ty;
    float inv = expf(-(float)tx * (9.210340371976184f / 32.0f));
    float f = (float)t * inv;
    cosT[t*32 + tx] = cosf(f);
    sinT[t*32 + tx] = sinf(f);
  }
}

// ---- GEMM (R8-verified best): 128x128, BK=64, 4 waves, dbuf + vmcnt(8), hoisted ----
// A: [M][K] bf16 row-major. BT: [N][K] bf16 (B^T, K-contiguous).
template<int N, int K, int EPI>
__global__ __launch_bounds__(256)
void k_gemm(const unsigned short* __restrict__ Ag,
            const unsigned short* __restrict__ BT,
            const float* __restrict__ bias,
            const float* __restrict__ cosT,
            const float* __restrict__ sinT,
            unsigned short* __restrict__ Qh,
            unsigned short* __restrict__ Kh,
            unsigned short* __restrict__ VhT,
            float* __restrict__ outF) {
  __shared__ alignas(16) unsigned short As[2][128*64];
  __shared__ alignas(16) unsigned short Bs[2][128*64];
  const int tid  = threadIdx.x;
  const int lane = tid & 63;
  const int wv   = tid >> 6;
  const int wm   = wv >> 1, wn = wv & 1;
  const int l15  = lane & 15, l4 = lane >> 4;
  // XCD-aware bijective swizzle (grid % 8 == 0), n-fastest within chunk.
  const int NT  = N / 128;
  const int id  = ((int)blockIdx.x & 7) * ((int)gridDim.x >> 3) + ((int)blockIdx.x >> 3);
  const int m0  = (id / NT) * 128;
  const int n0  = (id % NT) * 128;

  f32x4 acc[4][4] = {};

  // ---- hoisted LDS read pointers (K-loop invariant; row&7 == l15&7) ----
  const int g0 = l4 ^ (l15 & 7);          // ks=0 granule
  const int g1 = (4 + l4) ^ (l15 & 7);    // ks=1 granule
  const int rowA = wm*64 + l15, rowB = wn*64 + l15;
  const unsigned short* aRd0k0 = &As[0][rowA*64 + g0*8];
  const unsigned short* aRd0k1 = &As[0][rowA*64 + g1*8];
  const unsigned short* aRd1k0 = &As[1][rowA*64 + g0*8];
  const unsigned short* aRd1k1 = &As[1][rowA*64 + g1*8];
  const unsigned short* bRd0k0 = &Bs[0][rowB*64 + g0*8];
  const unsigned short* bRd0k1 = &Bs[0][rowB*64 + g1*8];
  const unsigned short* bRd1k0 = &Bs[1][rowB*64 + g0*8];
  const unsigned short* bRd1k1 = &Bs[1][rowB*64 + g1*8];

  // ---- hoisted staging offsets ----
  const int srow = wv*8 + (lane >> 3);                 // row within 32-row unit
  const int sg   = (lane & 7) ^ ((lane >> 3) & 7);     // granule (it/wv-invariant)
  const int voff = srow*K + sg*8;                      // per-lane, A and B identical
  const int aUni = m0*K, bUni = n0*K;
  const int ldsD = wv*512;                             // wave's LDS dest (elements)

#define STG(BUF, KT) do { \
  const int _u = (KT)*64; \
  _Pragma("unroll") for (int it = 0; it < 4; ++it) { \
    gload16(Ag + (aUni + it*(32*K) + _u) + voff, (void*)(&As[BUF][it*2048 + ldsD])); \
    gload16(BT + (bUni + it*(32*K) + _u) + voff, (void*)(&Bs[BUF][it*2048 + ldsD])); \
  } \
} while (0)

#define CMP(AK0, AK1, BK0, BK1) do { \
  bf16x8 afr[4][2], bfr[4][2]; \
  _Pragma("unroll") for (int mi = 0; mi < 4; ++mi) { \
    afr[mi][0] = *(const bf16x8*)((AK0) + mi*1024); \
    afr[mi][1] = *(const bf16x8*)((AK1) + mi*1024); \
    bfr[mi][0] = *(const bf16x8*)((BK0) + mi*1024); \
    bfr[mi][1] = *(const bf16x8*)((BK1) + mi*1024); \
  } \
  __builtin_amdgcn_s_setprio(1); \
  _Pragma("unroll") for (int ks = 0; ks < 2; ++ks) \
  _Pragma("unroll") for (int mi = 0; mi < 4; ++mi) \
  _Pragma("unroll") for (int ni = 0; ni < 4; ++ni) \
    acc[mi][ni] = __builtin_amdgcn_mfma_f32_16x16x32_bf16( \
        afr[mi][ks], bfr[ni][ks], acc[mi][ni], 0, 0, 0); \
  __builtin_amdgcn_s_setprio(0); \
} while (0)

  STG(0, 0);
  #pragma unroll 1
  for (int i = 0; i < K/128; ++i) {
    STG(1, 2*i + 1);            // prefetch odd tile into buf1
    VMC(8);                     // buf0's 8 loads done; prefetch in flight
    BAR();
    CMP(aRd0k0, aRd0k1, bRd0k0, bRd0k1);
    BAR();
    if (i + 1 < K/128) {
      STG(0, 2*i + 2);          // prefetch next even tile into buf0
      VMC(8);
    } else {
      VMC(0);
    }
    BAR();
    CMP(aRd1k0, aRd1k1, bRd1k0, bRd1k1);
    BAR();
  }
#undef STG
#undef CMP

  // epilogue. D layout: col = lane&15, row = (lane>>4)*4 + j  [m89/m91]
  if (EPI == 0) {
    const int ncol = n0 + wn*64;            // wave spans exactly one (part, head)
    const int part = ncol >> 10;            // 0=Q 1=K 2=V
    const int hid  = (ncol & 1023) >> 6;
    unsigned short* dstQK = (part == 0) ? Qh : Kh;
    #pragma unroll
    for (int mi = 0; mi < 4; ++mi) {
      #pragma unroll
      for (int j = 0; j < 4; ++j) {
        int row = m0 + wm*64 + mi*16 + l4*4 + j;
        int bb = row >> 11, tt = row & 2047;
        if (part < 2) {
          size_t base = ((size_t)((bb*NH_ + hid) * T_ + tt)) * HD_;
          #pragma unroll
          for (int ni = 0; ni < 2; ++ni) {
            int d = ni*16 + l15;
            float a1 = acc[mi][ni][j]     + bias[ncol + d];
            float a2 = acc[mi][ni + 2][j] + bias[ncol + d + 32];
            float cv = cosT[tt*32 + d], sv = sinT[tt*32 + d];
            float o1 = a1*cv - a2*sv;
            float o2 = a2*cv + a1*sv;
            // Q: fold 1/sqrt(64) * log2(e) so attention works in exp2 domain
            if (part == 0) { o1 *= 0.18033688011112042f; o2 *= 0.18033688011112042f; }
            dstQK[base + d]      = f2bf(o1);
            dstQK[base + d + 32] = f2bf(o2);
          }
        } else {
          #pragma unroll
          for (int ni = 0; ni < 4; ++ni) {
            int d = ni*16 + l15;
            float av = acc[mi][ni][j] + bias[ncol + d];
            VhT[((size_t)((bb*NH_ + hid) * HD_ + d)) * T_ + tt] = f2bf(av);
          }
        }
      }
    }
  } else {
    #pragma unroll
    for (int mi = 0; mi < 4; ++mi)
      #pragma unroll
      for (int ni = 0; ni < 4; ++ni)
        #pragma unroll
        for (int j = 0; j < 4; ++j) {
          int row = m0 + wm*64 + mi*16 + l4*4 + j;
          int col = n0 + wn*64 + ni*16 + l15;
          outF[(size_t)row * N + col] = acc[mi][ni][j] + bias[col];
        }
  }
}

// ---------------- flash attention (causal), 32x32 MFMA, swapped QK^T ----------------
// R18: reg-staged K/V + 72-elem (144B) padded LDS rows -> bank base (4r+4g)%32
// spreads with row; read/write patterns land at the uniform 8 dwords/bank minimum
// (XOR swizzle dropped; conflicts were structural at 128B rows under gload_lds).
// T14 async split: global loads for tile t+1 issue before compute(t); ds_writes
// land after, into the other buffer; ONE __syncthreads per tile.
// Qh pre-scaled by 0.125*log2(e); softmax via exp2. Lane l owns q-row (l&31).
#define LDW 72   // padded LDS row length (elements)
__global__ __launch_bounds__(256, 3)
void k_attn(const unsigned short* __restrict__ Qh,
            const unsigned short* __restrict__ Kh,
            const unsigned short* __restrict__ VhT,
            unsigned short* __restrict__ Y) {
  __shared__ alignas(16) unsigned short Ks[2][64*LDW];   // [key][d], padded rows
  __shared__ alignas(16) unsigned short Vs[2][64*LDW];   // [d][key], padded rows
  const int tid  = threadIdx.x;
  const int lane = tid & 63;
  const int wv   = tid >> 6;
  const int l31  = lane & 31;
  const int h    = lane >> 5;
  const int bh   = blockIdx.x & 63;
  const int qb   = 15 - (blockIdx.x >> 6);          // balanced qb spread per CU
  const int r32  = qb*128 + wv*32;                  // wave's first q-row
  const int nt   = 2*qb + 2;
  const int qg   = r32 + l31;                       // this lane's q-row (global)

  // Q B-frags: qf[i] = Q[qg][d = i*16 + h*8 + e]
  bf16x8 qf[4];
  #pragma unroll
  for (int i = 0; i < 4; ++i)
    qf[i] = *(const bf16x8*)(Qh + ((size_t)(bh*T_ + qg))*HD_ + i*16 + h*8);

  float m_r = -1e30f, l_r = 0.f;
  f32x16 o[2] = {};   // o[dblk][r]: O[q = qg][d = dblk*32 + (r&3)+8*(r>>2)+4*h]

  // ---- reg-staged K/V: thread covers granules {tid, tid+256} of each operand ----
  const int srow  = tid >> 3;                       // 0..31
  const int sslot = tid & 7;
  const unsigned short* kSrc0 = Kh  + ((size_t)(bh*T_ + srow))*HD_ + sslot*8;
  const unsigned short* kSrc1 = Kh  + ((size_t)(bh*T_ + 32 + srow))*HD_ + sslot*8;
  const unsigned short* vSrc0 = VhT + ((size_t)(bh*HD_ + srow))*T_ + sslot*8;
  const unsigned short* vSrc1 = VhT + ((size_t)(bh*HD_ + 32 + srow))*T_ + sslot*8;
  const int wOff0 = srow*LDW + sslot*8;
  const int wOff1 = (32 + srow)*LDW + sslot*8;

  uint4 kr0, kr1, vr0, vr1;
  auto ldg = [&](int jt) {
    kr0 = *(const uint4*)(kSrc0 + (size_t)jt*64*HD_);
    kr1 = *(const uint4*)(kSrc1 + (size_t)jt*64*HD_);
    vr0 = *(const uint4*)(vSrc0 + jt*64);
    vr1 = *(const uint4*)(vSrc1 + jt*64);
  };
  auto wst = [&](int buf) {
    *(uint4*)(&Ks[buf][wOff0]) = kr0;
    *(uint4*)(&Ks[buf][wOff1]) = kr1;
    *(uint4*)(&Vs[buf][wOff0]) = vr0;
    *(uint4*)(&Vs[buf][wOff1]) = vr1;
  };

  ldg(0); wst(0);
  __syncthreads();
  int cur = 0;

  for (int jt = 0; jt < nt; ++jt) {
    const bool pf = (jt + 1 < nt);
    if (pf) ldg(jt + 1);          // global loads fly during compute

    if (jt*64 <= r32 + 31) {      // wave-uniform skip of fully-masked tiles
      const unsigned short* kb_ = &Ks[cur][l31*LDW + h*8];
      const unsigned short* vb_ = &Vs[cur][l31*LDW + h*8];

      // S^T: s[kb][r] = S[key = jt*64+kb*32+(r&3)+8*(r>>2)+4*h][q = qg]
      f32x16 s[2] = {f32x16{0}, f32x16{0}};
      __builtin_amdgcn_s_setprio(1);
      #pragma unroll
      for (int kb = 0; kb < 2; ++kb)
        #pragma unroll
        for (int i = 0; i < 4; ++i) {
          bf16x8 kf = *(const bf16x8*)(kb_ + kb*32*LDW + i*16);
          s[kb] = __builtin_amdgcn_mfma_f32_32x32x16_bf16(kf, qf[i], s[kb], 0, 0, 0);
        }
      __builtin_amdgcn_s_setprio(0);

      // extract + causal mask (diagonal tiles only)
      float p[2][16];
      const bool diag = (jt + 1)*64 > r32;
      #pragma unroll
      for (int kb = 0; kb < 2; ++kb)
        #pragma unroll
        for (int r = 0; r < 16; ++r) {
          float v = s[kb][r];
          if (diag) {
            int key = jt*64 + kb*32 + (r & 3) + 8*(r >> 2) + 4*h;
            v = (key > qg) ? -1e30f : v;
          }
          p[kb][r] = v;
        }

      // row max: in-lane tree + one cross-half swap
      float mx[16];
      #pragma unroll
      for (int r = 0; r < 16; ++r) mx[r] = fmaxf(p[0][r], p[1][r]);
      #pragma unroll
      for (int st = 8; st > 0; st >>= 1)
        #pragma unroll
        for (int r = 0; r < 8; ++r)
          if (r < st) mx[r] = fmaxf(mx[r], mx[r + st]);
      float tm = fmaxf(mx[0], __shfl_xor(mx[0], 32));

      // defer-max (T13): only rescale when tile max outgrows running max by >8
      if (!__all(tm <= m_r + 8.0f)) {
        float mn = fmaxf(m_r, tm);
        float scale = exp2f(m_r - mn);
        m_r = mn;
        l_r *= scale;
        #pragma unroll
        for (int dblk = 0; dblk < 2; ++dblk)
          #pragma unroll
          for (int r = 0; r < 16; ++r)
            o[dblk][r] *= scale;
      }

      #pragma unroll
      for (int kb = 0; kb < 2; ++kb)
        #pragma unroll
        for (int r = 0; r < 16; ++r)
          p[kb][r] = exp2f(p[kb][r] - m_r);

      float sm[16];
      #pragma unroll
      for (int r = 0; r < 16; ++r) sm[r] = p[0][r] + p[1][r];
      #pragma unroll
      for (int st = 8; st > 0; st >>= 1)
        #pragma unroll
        for (int r = 0; r < 8; ++r)
          if (r < st) sm[r] += sm[r + st];
      l_r += sm[0] + __shfl_xor(sm[0], 32);

      // PV per key-block: P B-frags via cvt_pk + ONE swap per pair (pre-selected).
      #pragma unroll
      for (int kb = 0; kb < 2; ++kb) {
        uint32_t a01 = cvtpk(p[kb][0],  p[kb][1]);
        uint32_t a23 = cvtpk(p[kb][2],  p[kb][3]);
        uint32_t a45 = cvtpk(p[kb][4],  p[kb][5]);
        uint32_t a67 = cvtpk(p[kb][6],  p[kb][7]);
        uint32_t b01 = cvtpk(p[kb][8],  p[kb][9]);
        uint32_t b23 = cvtpk(p[kb][10], p[kb][11]);
        uint32_t b45 = cvtpk(p[kb][12], p[kb][13]);
        uint32_t b67 = cvtpk(p[kb][14], p[kb][15]);
        uint32_t s1 = h ? a01 : a45, s2 = h ? a23 : a67;   // send what partner needs
        uint32_t s3 = h ? b01 : b45, s4 = h ? b23 : b67;
        uint32_t x1 = __shfl_xor(s1, 32), x2 = __shfl_xor(s2, 32);
        uint32_t x3 = __shfl_xor(s3, 32), x4 = __shfl_xor(s4, 32);
        union { bf16x8 v; uint32_t d[4]; } f0, f1;
        f0.d[0] = h ? x1 : a01;  f0.d[1] = h ? x2 : a23;
        f0.d[2] = h ? a45 : x1;  f0.d[3] = h ? a67 : x2;
        f1.d[0] = h ? x3 : b01;  f1.d[1] = h ? x4 : b23;
        f1.d[2] = h ? b45 : x3;  f1.d[3] = h ? b67 : x4;

        __builtin_amdgcn_s_setprio(1);
        #pragma unroll
        for (int koff = 0; koff < 2; ++koff) {
          bf16x8 pf = koff ? f1.v : f0.v;
          #pragma unroll
          for (int dblk = 0; dblk < 2; ++dblk) {
            // V[key-chunk = kb*32+koff*16+h*8][d-row = dblk*32+l31]
            bf16x8 vf = *(const bf16x8*)(vb_ + dblk*32*LDW + kb*32 + koff*16);
            // A = V^T (row=d, lane-local l31), B = P (col=q, lane-local l31)
            o[dblk] = __builtin_amdgcn_mfma_f32_32x32x16_bf16(vf, pf, o[dblk], 0, 0, 0);
          }
        }
        __builtin_amdgcn_s_setprio(0);
      }
    }

    if (pf) wst(cur ^ 1);         // compiler inserts exact vmcnt before writes
    __syncthreads();              // writes visible; closes reads of cur
    cur ^= 1;
  }

  // epilogue: lane-local normalize, packed ushort4 stores
  int b = bh >> 4, hd = bh & 15;
  float rinv = 1.0f / l_r;
  unsigned short* yrow = Y + ((size_t)(b*T_ + r32 + l31))*C_ + hd*64;
  #pragma unroll
  for (int dblk = 0; dblk < 2; ++dblk)
    #pragma unroll
    for (int g2 = 0; g2 < 4; ++g2) {
      ushort4 o4;
      o4.x = f2bf(o[dblk][g2*4 + 0] * rinv);
      o4.y = f2bf(o[dblk][g2*4 + 1] * rinv);
      o4.z = f2bf(o[dblk][g2*4 + 2] * rinv);
      o4.w = f2bf(o[dblk][g2*4 + 3] * rinv);
      *(ushort4*)(yrow + dblk*32 + g2*8 + 4*h) = o4;
    }
}

// ---------------- host ----------------

extern "C" void kernel_launch(void* const* d_in, const int* in_sizes, int n_in,
                              void* d_out, int out_size, void* d_ws, size_t ws_size,
                              hipStream_t stream) {
  const float* x      = (const float*)d_in[0];
  const float* W_qkv  = (const float*)d_in[1];
  const float* b_qkv  = (const float*)d_in[2];
  const float* W_proj = (const float*)d_in[3];
  const float* b_proj = (const float*)d_in[4];
  float* out = (float*)d_out;

  char* ws = (char*)d_ws;
  size_t off = 0;
  auto alloc = [&](size_t bytes) {
    void* p = ws + off; off += (bytes + 255) & ~(size_t)255; return p;
  };
  unsigned short* xb     = (unsigned short*)alloc((size_t)M_ * C_ * 2);  // also reused as Y
  unsigned short* WqkvT  = (unsigned short*)alloc((size_t)3 * C_ * C_ * 2);
  unsigned short* WprojT = (unsigned short*)alloc((size_t)C_ * C_ * 2);
  unsigned short* Qh     = (unsigned short*)alloc((size_t)M_ * C_ * 2);
  unsigned short* Kh     = (unsigned short*)alloc((size_t)M_ * C_ * 2);
  unsigned short* VhT    = (unsigned short*)alloc((size_t)M_ * C_ * 2);
  float* cosT = (float*)alloc((size_t)T_ * 32 * 4);
  float* sinT = (float*)alloc((size_t)T_ * 32 * 4);
  unsigned short* Y = xb;   // xb dead after QKV GEMM; attention output aliases it

  // fused prep: 8192 cvt + 3072 qkvT + 1024 projT + 256 rope = 12544 blocks
  k_prep<<<dim3(12544), 256, 0, stream>>>(x, xb, W_qkv, WqkvT, W_proj, WprojT,
                                          cosT, sinT);

  // QKV: 64 m-tiles x 24 n-tiles = 1536 blocks (1D, XCD-swizzled in-kernel)
  k_gemm<3*C_, C_, 0><<<dim3(1536), 256, 0, stream>>>(
      xb, WqkvT, b_qkv, cosT, sinT, Qh, Kh, VhT, nullptr);

  // attn: QBLK=128, 4 waves/block; 16 qb x 64 bh = 1024 blocks
  k_attn<<<dim3(T_/128 * BH_), 256, 0, stream>>>(Qh, Kh, VhT, Y);

  // proj: 64 x 8 = 512 blocks
  k_gemm<C_, C_, 1><<<dim3(512), 256, 0, stream>>>(
      Y, WprojT, b_proj, nullptr, nullptr, nullptr, nullptr, nullptr, out);
}

// Round 19
// 188.357 us; speedup vs baseline: 1.3244x; 1.0254x over previous
//
#include <hip/hip_runtime.h>
#include <stdint.h>

#define B_  4
#define T_  2048
#define C_  1024
#define NH_ 16
#define HD_ 64
#define BH_ (B_*NH_)   // 64
#define M_  (B_*T_)    // 8192

using f32x4  = __attribute__((ext_vector_type(4))) float;
using f32x16 = __attribute__((ext_vector_type(16))) float;
using bf16x8 = __attribute__((ext_vector_type(8))) short;   // 8 bf16 in 4 VGPRs

__device__ __forceinline__ unsigned short f2bf(float x) {
  union { float f; uint32_t u; } v; v.f = x;
  uint32_t u = v.u;
  return (unsigned short)((u + 0x7FFFu + ((u >> 16) & 1u)) >> 16);  // RNE
}

__device__ __forceinline__ uint32_t cvtpk(float a, float b) {
  uint32_t r;
  asm("v_cvt_pk_bf16_f32 %0, %1, %2" : "=v"(r) : "v"(a), "v"(b));
  return r;
}

// async global->LDS, 16B per lane. lds ptr must be wave-uniform base; HW adds lane*16.
__device__ __forceinline__ void gload16(const void* g, void* l) {
  __builtin_amdgcn_global_load_lds(
      (const __attribute__((address_space(1))) void*)g,
      (__attribute__((address_space(3))) void*)l, 16, 0, 0);
}

#define BAR() do { asm volatile("" ::: "memory"); __builtin_amdgcn_s_barrier(); \
                   asm volatile("" ::: "memory"); } while (0)
#define VMC(N) asm volatile("s_waitcnt vmcnt(" #N ")" ::: "memory")

// ---------------- fused prep: cvt + W transposes + rope tables, ONE launch --------
__global__ __launch_bounds__(256)
void k_prep(const float* __restrict__ x,      unsigned short* __restrict__ xb,
            const float* __restrict__ Wqkv,   unsigned short* __restrict__ WqkvT,
            const float* __restrict__ Wproj,  unsigned short* __restrict__ WprojT,
            float* __restrict__ cosT, float* __restrict__ sinT) {
  __shared__ float tile[32][33];
  const int blk = blockIdx.x;
  const int tid = threadIdx.x;
  if (blk < 8192) {                       // ---- cvt bf16
    int i = (blk * 256 + tid) * 4;
    float4 v = *(const float4*)(x + i);
    ushort4 o;
    o.x = f2bf(v.x); o.y = f2bf(v.y); o.z = f2bf(v.z); o.w = f2bf(v.w);
    *(ushort4*)(xb + i) = o;
    return;
  }
  const int tx = tid & 31, ty = tid >> 5; // (32,8) shape for the rest
  if (blk < 12288) {                      // ---- W transposes
    const float* W; unsigned short* WT; int N, local;
    if (blk < 11264) { W = Wqkv;  WT = WqkvT;  N = 3*C_; local = blk - 8192; }
    else             { W = Wproj; WT = WprojT; N = C_;   local = blk - 11264; }
    const int NT = N / 32;
    const int bx = local % NT, by = local / NT;
    #pragma unroll
    for (int i = 0; i < 32; i += 8)
      tile[ty + i][tx] = W[(size_t)(by*32 + ty + i) * N + bx*32 + tx];
    __syncthreads();
    #pragma unroll
    for (int i = 0; i < 32; i += 8)
      WT[(size_t)(bx*32 + ty + i) * C_ + by*32 + tx] = f2bf(tile[tx][ty + i]);
    return;
  }
  {                                       // ---- rope tables
    int t = (blk - 12288) * 8 + ty;
    float inv = expf(-(float)tx * (9.210340371976184f / 32.0f));
    float f = (float)t * inv;
    cosT[t*32 + tx] = cosf(f);
    sinT[t*32 + tx] = sinf(f);
  }
}

// ---- GEMM (R8 schedule + L2-group block mapping): 128x128, BK=64, 4 waves ----
// R19: staging loads are latency-critical (depth-1 prefetch covers L2 hits but
// not HBM misses). Map blocks so each XCD works on 8m x GN n sub-groups whose
// A+B panels fit the 4MB per-XCD L2: QKV GN=6 (2+1.5MB), proj GN=8 (2+2MB).
// A: [M][K] bf16 row-major. BT: [N][K] bf16 (B^T, K-contiguous).
template<int N, int K, int EPI>
__global__ __launch_bounds__(256)
void k_gemm(const unsigned short* __restrict__ Ag,
            const unsigned short* __restrict__ BT,
            const float* __restrict__ bias,
            const float* __restrict__ cosT,
            const float* __restrict__ sinT,
            unsigned short* __restrict__ Qh,
            unsigned short* __restrict__ Kh,
            unsigned short* __restrict__ VhT,
            float* __restrict__ outF) {
  __shared__ alignas(16) unsigned short As[2][128*64];
  __shared__ alignas(16) unsigned short Bs[2][128*64];
  const int tid  = threadIdx.x;
  const int lane = tid & 63;
  const int wv   = tid >> 6;
  const int wm   = wv >> 1, wn = wv & 1;
  const int l15  = lane & 15, l4 = lane >> 4;
  // XCD-aware L2-group mapping (bijective; grid % 8 == 0).
  // xcd owns m-tiles [xcd*8, xcd*8+8); within chunk, n-fastest inside 8m x GN.
  constexpr int GN = (N == 3072) ? 6 : 8;      // n-tiles per L2 sub-group
  const int xcd = (int)blockIdx.x & 7;
  const int loc = (int)blockIdx.x >> 3;        // 0..cpx-1
  const int sub = loc / (8*GN);
  const int wit = loc % (8*GN);
  const int m0  = (xcd*8 + wit / GN) * 128;
  const int n0  = (sub*GN + wit % GN) * 128;

  f32x4 acc[4][4] = {};

  // ---- hoisted LDS read pointers (K-loop invariant; row&7 == l15&7) ----
  const int g0 = l4 ^ (l15 & 7);          // ks=0 granule
  const int g1 = (4 + l4) ^ (l15 & 7);    // ks=1 granule
  const int rowA = wm*64 + l15, rowB = wn*64 + l15;
  const unsigned short* aRd0k0 = &As[0][rowA*64 + g0*8];
  const unsigned short* aRd0k1 = &As[0][rowA*64 + g1*8];
  const unsigned short* aRd1k0 = &As[1][rowA*64 + g0*8];
  const unsigned short* aRd1k1 = &As[1][rowA*64 + g1*8];
  const unsigned short* bRd0k0 = &Bs[0][rowB*64 + g0*8];
  const unsigned short* bRd0k1 = &Bs[0][rowB*64 + g1*8];
  const unsigned short* bRd1k0 = &Bs[1][rowB*64 + g0*8];
  const unsigned short* bRd1k1 = &Bs[1][rowB*64 + g1*8];

  // ---- hoisted staging offsets ----
  const int srow = wv*8 + (lane >> 3);                 // row within 32-row unit
  const int sg   = (lane & 7) ^ ((lane >> 3) & 7);     // granule (it/wv-invariant)
  const int voff = srow*K + sg*8;                      // per-lane, A and B identical
  const int aUni = m0*K, bUni = n0*K;
  const int ldsD = wv*512;                             // wave's LDS dest (elements)

#define STG(BUF, KT) do { \
  const int _u = (KT)*64; \
  _Pragma("unroll") for (int it = 0; it < 4; ++it) { \
    gload16(Ag + (aUni + it*(32*K) + _u) + voff, (void*)(&As[BUF][it*2048 + ldsD])); \
    gload16(BT + (bUni + it*(32*K) + _u) + voff, (void*)(&Bs[BUF][it*2048 + ldsD])); \
  } \
} while (0)

#define CMP(AK0, AK1, BK0, BK1) do { \
  bf16x8 afr[4][2], bfr[4][2]; \
  _Pragma("unroll") for (int mi = 0; mi < 4; ++mi) { \
    afr[mi][0] = *(const bf16x8*)((AK0) + mi*1024); \
    afr[mi][1] = *(const bf16x8*)((AK1) + mi*1024); \
    bfr[mi][0] = *(const bf16x8*)((BK0) + mi*1024); \
    bfr[mi][1] = *(const bf16x8*)((BK1) + mi*1024); \
  } \
  __builtin_amdgcn_s_setprio(1); \
  _Pragma("unroll") for (int ks = 0; ks < 2; ++ks) \
  _Pragma("unroll") for (int mi = 0; mi < 4; ++mi) \
  _Pragma("unroll") for (int ni = 0; ni < 4; ++ni) \
    acc[mi][ni] = __builtin_amdgcn_mfma_f32_16x16x32_bf16( \
        afr[mi][ks], bfr[ni][ks], acc[mi][ni], 0, 0, 0); \
  __builtin_amdgcn_s_setprio(0); \
} while (0)

  STG(0, 0);
  #pragma unroll 1
  for (int i = 0; i < K/128; ++i) {
    STG(1, 2*i + 1);            // prefetch odd tile into buf1
    VMC(8);                     // buf0's 8 loads done; prefetch in flight
    BAR();
    CMP(aRd0k0, aRd0k1, bRd0k0, bRd0k1);
    BAR();
    if (i + 1 < K/128) {
      STG(0, 2*i + 2);          // prefetch next even tile into buf0
      VMC(8);
    } else {
      VMC(0);
    }
    BAR();
    CMP(aRd1k0, aRd1k1, bRd1k0, bRd1k1);
    BAR();
  }
#undef STG
#undef CMP

  // epilogue. D layout: col = lane&15, row = (lane>>4)*4 + j  [m89/m91]
  if (EPI == 0) {
    const int ncol = n0 + wn*64;            // wave spans exactly one (part, head)
    const int part = ncol >> 10;            // 0=Q 1=K 2=V
    const int hid  = (ncol & 1023) >> 6;
    unsigned short* dstQK = (part == 0) ? Qh : Kh;
    #pragma unroll
    for (int mi = 0; mi < 4; ++mi) {
      #pragma unroll
      for (int j = 0; j < 4; ++j) {
        int row = m0 + wm*64 + mi*16 + l4*4 + j;
        int bb = row >> 11, tt = row & 2047;
        if (part < 2) {
          size_t base = ((size_t)((bb*NH_ + hid) * T_ + tt)) * HD_;
          #pragma unroll
          for (int ni = 0; ni < 2; ++ni) {
            int d = ni*16 + l15;
            float a1 = acc[mi][ni][j]     + bias[ncol + d];
            float a2 = acc[mi][ni + 2][j] + bias[ncol + d + 32];
            float cv = cosT[tt*32 + d], sv = sinT[tt*32 + d];
            float o1 = a1*cv - a2*sv;
            float o2 = a2*cv + a1*sv;
            // Q: fold 1/sqrt(64) * log2(e) so attention works in exp2 domain
            if (part == 0) { o1 *= 0.18033688011112042f; o2 *= 0.18033688011112042f; }
            dstQK[base + d]      = f2bf(o1);
            dstQK[base + d + 32] = f2bf(o2);
          }
        } else {
          #pragma unroll
          for (int ni = 0; ni < 4; ++ni) {
            int d = ni*16 + l15;
            float av = acc[mi][ni][j] + bias[ncol + d];
            VhT[((size_t)((bb*NH_ + hid) * HD_ + d)) * T_ + tt] = f2bf(av);
          }
        }
      }
    }
  } else {
    #pragma unroll
    for (int mi = 0; mi < 4; ++mi)
      #pragma unroll
      for (int ni = 0; ni < 4; ++ni)
        #pragma unroll
        for (int j = 0; j < 4; ++j) {
          int row = m0 + wm*64 + mi*16 + l4*4 + j;
          int col = n0 + wn*64 + ni*16 + l15;
          outF[(size_t)row * N + col] = acc[mi][ni][j] + bias[col];
        }
  }
}

// ---------------- flash attention (causal), 32x32 MFMA, swapped QK^T ----------------
// (R18-verified: reg-staged K/V + 72-elem padded LDS rows, conflict-free; T14 split.)
// Qh pre-scaled by 0.125*log2(e); softmax via exp2. Lane l owns q-row (l&31).
#define LDW 72   // padded LDS row length (elements)
__global__ __launch_bounds__(256, 3)
void k_attn(const unsigned short* __restrict__ Qh,
            const unsigned short* __restrict__ Kh,
            const unsigned short* __restrict__ VhT,
            unsigned short* __restrict__ Y) {
  __shared__ alignas(16) unsigned short Ks[2][64*LDW];   // [key][d], padded rows
  __shared__ alignas(16) unsigned short Vs[2][64*LDW];   // [d][key], padded rows
  const int tid  = threadIdx.x;
  const int lane = tid & 63;
  const int wv   = tid >> 6;
  const int l31  = lane & 31;
  const int h    = lane >> 5;
  const int bh   = blockIdx.x & 63;
  const int qb   = 15 - (blockIdx.x >> 6);          // balanced qb spread per CU
  const int r32  = qb*128 + wv*32;                  // wave's first q-row
  const int nt   = 2*qb + 2;
  const int qg   = r32 + l31;                       // this lane's q-row (global)

  // Q B-frags: qf[i] = Q[qg][d = i*16 + h*8 + e]
  bf16x8 qf[4];
  #pragma unroll
  for (int i = 0; i < 4; ++i)
    qf[i] = *(const bf16x8*)(Qh + ((size_t)(bh*T_ + qg))*HD_ + i*16 + h*8);

  float m_r = -1e30f, l_r = 0.f;
  f32x16 o[2] = {};   // o[dblk][r]: O[q = qg][d = dblk*32 + (r&3)+8*(r>>2)+4*h]

  // ---- reg-staged K/V: thread covers granules {tid, tid+256} of each operand ----
  const int srow  = tid >> 3;                       // 0..31
  const int sslot = tid & 7;
  const unsigned short* kSrc0 = Kh  + ((size_t)(bh*T_ + srow))*HD_ + sslot*8;
  const unsigned short* kSrc1 = Kh  + ((size_t)(bh*T_ + 32 + srow))*HD_ + sslot*8;
  const unsigned short* vSrc0 = VhT + ((size_t)(bh*HD_ + srow))*T_ + sslot*8;
  const unsigned short* vSrc1 = VhT + ((size_t)(bh*HD_ + 32 + srow))*T_ + sslot*8;
  const int wOff0 = srow*LDW + sslot*8;
  const int wOff1 = (32 + srow)*LDW + sslot*8;

  uint4 kr0, kr1, vr0, vr1;
  auto ldg = [&](int jt) {
    kr0 = *(const uint4*)(kSrc0 + (size_t)jt*64*HD_);
    kr1 = *(const uint4*)(kSrc1 + (size_t)jt*64*HD_);
    vr0 = *(const uint4*)(vSrc0 + jt*64);
    vr1 = *(const uint4*)(vSrc1 + jt*64);
  };
  auto wst = [&](int buf) {
    *(uint4*)(&Ks[buf][wOff0]) = kr0;
    *(uint4*)(&Ks[buf][wOff1]) = kr1;
    *(uint4*)(&Vs[buf][wOff0]) = vr0;
    *(uint4*)(&Vs[buf][wOff1]) = vr1;
  };

  ldg(0); wst(0);
  __syncthreads();
  int cur = 0;

  for (int jt = 0; jt < nt; ++jt) {
    const bool pf = (jt + 1 < nt);
    if (pf) ldg(jt + 1);          // global loads fly during compute

    if (jt*64 <= r32 + 31) {      // wave-uniform skip of fully-masked tiles
      const unsigned short* kb_ = &Ks[cur][l31*LDW + h*8];
      const unsigned short* vb_ = &Vs[cur][l31*LDW + h*8];

      // S^T: s[kb][r] = S[key = jt*64+kb*32+(r&3)+8*(r>>2)+4*h][q = qg]
      f32x16 s[2] = {f32x16{0}, f32x16{0}};
      __builtin_amdgcn_s_setprio(1);
      #pragma unroll
      for (int kb = 0; kb < 2; ++kb)
        #pragma unroll
        for (int i = 0; i < 4; ++i) {
          bf16x8 kf = *(const bf16x8*)(kb_ + kb*32*LDW + i*16);
          s[kb] = __builtin_amdgcn_mfma_f32_32x32x16_bf16(kf, qf[i], s[kb], 0, 0, 0);
        }
      __builtin_amdgcn_s_setprio(0);

      // extract + causal mask (diagonal tiles only)
      float p[2][16];
      const bool diag = (jt + 1)*64 > r32;
      #pragma unroll
      for (int kb = 0; kb < 2; ++kb)
        #pragma unroll
        for (int r = 0; r < 16; ++r) {
          float v = s[kb][r];
          if (diag) {
            int key = jt*64 + kb*32 + (r & 3) + 8*(r >> 2) + 4*h;
            v = (key > qg) ? -1e30f : v;
          }
          p[kb][r] = v;
        }

      // row max: in-lane tree + one cross-half swap
      float mx[16];
      #pragma unroll
      for (int r = 0; r < 16; ++r) mx[r] = fmaxf(p[0][r], p[1][r]);
      #pragma unroll
      for (int st = 8; st > 0; st >>= 1)
        #pragma unroll
        for (int r = 0; r < 8; ++r)
          if (r < st) mx[r] = fmaxf(mx[r], mx[r + st]);
      float tm = fmaxf(mx[0], __shfl_xor(mx[0], 32));

      // defer-max (T13): only rescale when tile max outgrows running max by >8
      if (!__all(tm <= m_r + 8.0f)) {
        float mn = fmaxf(m_r, tm);
        float scale = exp2f(m_r - mn);
        m_r = mn;
        l_r *= scale;
        #pragma unroll
        for (int dblk = 0; dblk < 2; ++dblk)
          #pragma unroll
          for (int r = 0; r < 16; ++r)
            o[dblk][r] *= scale;
      }

      #pragma unroll
      for (int kb = 0; kb < 2; ++kb)
        #pragma unroll
        for (int r = 0; r < 16; ++r)
          p[kb][r] = exp2f(p[kb][r] - m_r);

      float sm[16];
      #pragma unroll
      for (int r = 0; r < 16; ++r) sm[r] = p[0][r] + p[1][r];
      #pragma unroll
      for (int st = 8; st > 0; st >>= 1)
        #pragma unroll
        for (int r = 0; r < 8; ++r)
          if (r < st) sm[r] += sm[r + st];
      l_r += sm[0] + __shfl_xor(sm[0], 32);

      // PV per key-block: P B-frags via cvt_pk + ONE swap per pair (pre-selected).
      #pragma unroll
      for (int kb = 0; kb < 2; ++kb) {
        uint32_t a01 = cvtpk(p[kb][0],  p[kb][1]);
        uint32_t a23 = cvtpk(p[kb][2],  p[kb][3]);
        uint32_t a45 = cvtpk(p[kb][4],  p[kb][5]);
        uint32_t a67 = cvtpk(p[kb][6],  p[kb][7]);
        uint32_t b01 = cvtpk(p[kb][8],  p[kb][9]);
        uint32_t b23 = cvtpk(p[kb][10], p[kb][11]);
        uint32_t b45 = cvtpk(p[kb][12], p[kb][13]);
        uint32_t b67 = cvtpk(p[kb][14], p[kb][15]);
        uint32_t s1 = h ? a01 : a45, s2 = h ? a23 : a67;   // send what partner needs
        uint32_t s3 = h ? b01 : b45, s4 = h ? b23 : b67;
        uint32_t x1 = __shfl_xor(s1, 32), x2 = __shfl_xor(s2, 32);
        uint32_t x3 = __shfl_xor(s3, 32), x4 = __shfl_xor(s4, 32);
        union { bf16x8 v; uint32_t d[4]; } f0, f1;
        f0.d[0] = h ? x1 : a01;  f0.d[1] = h ? x2 : a23;
        f0.d[2] = h ? a45 : x1;  f0.d[3] = h ? a67 : x2;
        f1.d[0] = h ? x3 : b01;  f1.d[1] = h ? x4 : b23;
        f1.d[2] = h ? b45 : x3;  f1.d[3] = h ? b67 : x4;

        __builtin_amdgcn_s_setprio(1);
        #pragma unroll
        for (int koff = 0; koff < 2; ++koff) {
          bf16x8 pf = koff ? f1.v : f0.v;
          #pragma unroll
          for (int dblk = 0; dblk < 2; ++dblk) {
            // V[key-chunk = kb*32+koff*16+h*8][d-row = dblk*32+l31]
            bf16x8 vf = *(const bf16x8*)(vb_ + dblk*32*LDW + kb*32 + koff*16);
            // A = V^T (row=d, lane-local l31), B = P (col=q, lane-local l31)
            o[dblk] = __builtin_amdgcn_mfma_f32_32x32x16_bf16(vf, pf, o[dblk], 0, 0, 0);
          }
        }
        __builtin_amdgcn_s_setprio(0);
      }
    }

    if (pf) wst(cur ^ 1);         // compiler inserts exact vmcnt before writes
    __syncthreads();              // writes visible; closes reads of cur
    cur ^= 1;
  }

  // epilogue: lane-local normalize, packed ushort4 stores
  int b = bh >> 4, hd = bh & 15;
  float rinv = 1.0f / l_r;
  unsigned short* yrow = Y + ((size_t)(b*T_ + r32 + l31))*C_ + hd*64;
  #pragma unroll
  for (int dblk = 0; dblk < 2; ++dblk)
    #pragma unroll
    for (int g2 = 0; g2 < 4; ++g2) {
      ushort4 o4;
      o4.x = f2bf(o[dblk][g2*4 + 0] * rinv);
      o4.y = f2bf(o[dblk][g2*4 + 1] * rinv);
      o4.z = f2bf(o[dblk][g2*4 + 2] * rinv);
      o4.w = f2bf(o[dblk][g2*4 + 3] * rinv);
      *(ushort4*)(yrow + dblk*32 + g2*8 + 4*h) = o4;
    }
}

// ---------------- host ----------------

extern "C" void kernel_launch(void* const* d_in, const int* in_sizes, int n_in,
                              void* d_out, int out_size, void* d_ws, size_t ws_size,
                              hipStream_t stream) {
  const float* x      = (const float*)d_in[0];
  const float* W_qkv  = (const float*)d_in[1];
  const float* b_qkv  = (const float*)d_in[2];
  const float* W_proj = (const float*)d_in[3];
  const float* b_proj = (const float*)d_in[4];
  float* out = (float*)d_out;

  char* ws = (char*)d_ws;
  size_t off = 0;
  auto alloc = [&](size_t bytes) {
    void* p = ws + off; off += (bytes + 255) & ~(size_t)255; return p;
  };
  unsigned short* xb     = (unsigned short*)alloc((size_t)M_ * C_ * 2);  // also reused as Y
  unsigned short* WqkvT  = (unsigned short*)alloc((size_t)3 * C_ * C_ * 2);
  unsigned short* WprojT = (unsigned short*)alloc((size_t)C_ * C_ * 2);
  unsigned short* Qh     = (unsigned short*)alloc((size_t)M_ * C_ * 2);
  unsigned short* Kh     = (unsigned short*)alloc((size_t)M_ * C_ * 2);
  unsigned short* VhT    = (unsigned short*)alloc((size_t)M_ * C_ * 2);
  float* cosT = (float*)alloc((size_t)T_ * 32 * 4);
  float* sinT = (float*)alloc((size_t)T_ * 32 * 4);
  unsigned short* Y = xb;   // xb dead after QKV GEMM; attention output aliases it

  // fused prep: 8192 cvt + 3072 qkvT + 1024 projT + 256 rope = 12544 blocks
  k_prep<<<dim3(12544), 256, 0, stream>>>(x, xb, W_qkv, WqkvT, W_proj, WprojT,
                                          cosT, sinT);

  // QKV: 64 m-tiles x 24 n-tiles = 1536 blocks (1D, XCD/L2-grouped in-kernel)
  k_gemm<3*C_, C_, 0><<<dim3(1536), 256, 0, stream>>>(
      xb, WqkvT, b_qkv, cosT, sinT, Qh, Kh, VhT, nullptr);

  // attn: QBLK=128, 4 waves/block; 16 qb x 64 bh = 1024 blocks
  k_attn<<<dim3(T_/128 * BH_), 256, 0, stream>>>(Qh, Kh, VhT, Y);

  // proj: 64 x 8 = 512 blocks
  k_gemm<C_, C_, 1><<<dim3(512), 256, 0, stream>>>(
      Y, WprojT, b_proj, nullptr, nullptr, nullptr, nullptr, nullptr, out);
}